// Round 5
// baseline (603.914 us; speedup 1.0000x reference)
//
#include <hip/hip_runtime.h>
#include <hip/hip_bf16.h>
#include <cstdint>
#include <cstddef>

typedef unsigned short u16;
typedef __attribute__((ext_vector_type(8))) __bf16 bf16x8;
typedef __attribute__((ext_vector_type(4))) float f32x4;

#define AS1 __attribute__((address_space(1)))
#define AS3 __attribute__((address_space(3)))

__device__ __forceinline__ u16 f2bf(float f) {
    union { float f; uint32_t u; } v; v.f = f;
    uint32_t r = (v.u + 0x7FFFu + ((v.u >> 16) & 1u)) >> 16;
    return (u16)r;
}

__device__ __forceinline__ float bf2f(u16 b) {
    union { uint32_t u; float f; } v; v.u = ((uint32_t)b) << 16;
    return v.f;
}

__device__ __forceinline__ uint32_t pack_bf2(float lo, float hi) {
    __hip_bfloat162 p = __float22bfloat162_rn(float2{lo, hi});
    union { __hip_bfloat162 b; uint32_t u; } v; v.b = p;
    return v.u;
}

__device__ __forceinline__ f32x4 mfma16(bf16x8 a, bf16x8 b, f32x4 c) {
    return __builtin_amdgcn_mfma_f32_16x16x32_bf16(a, b, c, 0, 0, 0);
}

// async global->LDS, 16B per lane; lane i lands at base + i*16.
__device__ __forceinline__ void async16(const u16* g, u16* lds_uniform_base) {
    __builtin_amdgcn_global_load_lds((const AS1 void*)g, (AS3 void*)lds_uniform_base, 16, 0, 0);
}

// ------------------------------------------------------------ fused prep
// blocks [0,6144): x fp32 -> xb bf16 (4 elems/thread)
// blocks [6144,13056): 32x32 transpose+cast tiles of wq/wk/wv/wo/w1/w2
__global__ __launch_bounds__(256)
void k_prep(const float* __restrict__ x, u16* __restrict__ xb,
            const float* __restrict__ wq, const float* __restrict__ wk,
            const float* __restrict__ wv, const float* __restrict__ wo,
            const float* __restrict__ w1, const float* __restrict__ w2,
            u16* __restrict__ wqkvt, u16* __restrict__ wot,
            u16* __restrict__ w1t, u16* __restrict__ w2t)
{
    int bx = blockIdx.x;
    if (bx < 6144) {
        int i = (bx * 256 + threadIdx.x) * 4;
        float4 f = *(const float4*)(x + i);
        xb[i + 0] = f2bf(f.x); xb[i + 1] = f2bf(f.y);
        xb[i + 2] = f2bf(f.z); xb[i + 3] = f2bf(f.w);
        return;
    }
    int t = bx - 6144;
    const float* in; u16* out; int R, C;
    if (t < 2304) {
        int m = t / 576; t -= m * 576;
        R = 768; C = 768;
        in = (m == 0) ? wq : (m == 1) ? wk : (m == 2) ? wv : wo;
        out = (m < 3) ? wqkvt + (size_t)m * 768 * 768 : wot;
    } else if (t < 4608) {
        t -= 2304; in = w1; out = w1t; R = 768; C = 3072;
    } else {
        t -= 4608; in = w2; out = w2t; R = 3072; C = 768;
    }
    int tilesX = C >> 5;
    int c0 = (t % tilesX) * 32, r0 = (t / tilesX) * 32;
    __shared__ float tile[32][33];
    int tx = threadIdx.x & 31, ty = threadIdx.x >> 5;
    #pragma unroll
    for (int i = ty; i < 32; i += 8)
        tile[i][tx] = in[(size_t)(r0 + i) * C + c0 + tx];
    __syncthreads();
    #pragma unroll
    for (int i = ty; i < 32; i += 8)
        out[(size_t)(c0 + i) * R + r0 + tx] = f2bf(tile[tx][i]);
}

// ---------------------------------------------------------------- GEMM
// C[M,N] = (A[M,K] @ B(as Bt[N,K]) + bias) (+relu). XOR-swizzled LDS
// staging: (row, chunk) at slot row*4 + (chunk ^ ((row>>1)&3)).
template <bool RELU>
__global__ __launch_bounds__(256)
void k_gemm(const u16* __restrict__ A, const u16* __restrict__ Bt,
            const float* __restrict__ bias, u16* __restrict__ Cb,
            int M, int N, int K)
{
    __shared__ __align__(16) u16 lA[128 * 32];
    __shared__ __align__(16) u16 lB[128 * 32];
    const int tid = threadIdx.x;
    const int w = tid >> 6, lane = tid & 63;
    const int quad = lane >> 4, l15 = lane & 15;
    const int m0 = blockIdx.x * 128, n0 = blockIdx.y * 128;
    const int wm = (w >> 1) * 64, wn = (w & 1) * 64;
    const int sw = (quad ^ ((l15 >> 1) & 3)) * 8;

    const f32x4 fz = {0.f, 0.f, 0.f, 0.f};
    f32x4 acc[4][4];
    #pragma unroll
    for (int i = 0; i < 4; ++i)
        #pragma unroll
        for (int j = 0; j < 4; ++j) acc[i][j] = fz;

    for (int k0 = 0; k0 < K; k0 += 32) {
        #pragma unroll
        for (int r = 0; r < 2; ++r) {
            int c = r * 256 + tid;
            int row = c >> 2, ch = (c & 3) ^ ((row >> 1) & 3);
            async16(A + (size_t)(m0 + row) * K + k0 + ch * 8,
                    (u16*)lA + (size_t)(r * 256 + w * 64) * 8);
            async16(Bt + (size_t)(n0 + row) * K + k0 + ch * 8,
                    (u16*)lB + (size_t)(r * 256 + w * 64) * 8);
        }
        __syncthreads();
        bf16x8 af[4], bfr[4];
        #pragma unroll
        for (int i = 0; i < 4; ++i)
            af[i] = *(const bf16x8*)&lA[(wm + i * 16 + l15) * 32 + sw];
        #pragma unroll
        for (int j = 0; j < 4; ++j)
            bfr[j] = *(const bf16x8*)&lB[(wn + j * 16 + l15) * 32 + sw];
        #pragma unroll
        for (int i = 0; i < 4; ++i)
            #pragma unroll
            for (int j = 0; j < 4; ++j)
                acc[i][j] = mfma16(af[i], bfr[j], acc[i][j]);
        __syncthreads();
    }
    #pragma unroll
    for (int j = 0; j < 4; ++j) {
        int col = n0 + wn + j * 16 + l15;
        float bv = bias[col];
        #pragma unroll
        for (int i = 0; i < 4; ++i) {
            int row = m0 + wm + i * 16 + quad * 4;
            #pragma unroll
            for (int r = 0; r < 4; ++r) {
                float t = acc[i][j][r] + bv;
                if (RELU) t = fmaxf(t, 0.f);
                Cb[(size_t)(row + r) * N + col] = f2bf(t);
            }
        }
    }
}

// ------------------------------------------------- split-K partial GEMM
__global__ __launch_bounds__(256)
void k_gemm_part(const u16* __restrict__ A, const u16* __restrict__ Bt,
                 float* __restrict__ C0, float* __restrict__ C1,
                 int M, int N, int K, int Kh)
{
    __shared__ __align__(16) u16 lA[128 * 32];
    __shared__ __align__(16) u16 lB[128 * 32];
    const int tid = threadIdx.x;
    const int w = tid >> 6, lane = tid & 63;
    const int quad = lane >> 4, l15 = lane & 15;
    const int m0 = blockIdx.x * 128, n0 = blockIdx.y * 128;
    const int wm = (w >> 1) * 64, wn = (w & 1) * 64;
    const int sw = (quad ^ ((l15 >> 1) & 3)) * 8;
    const int kbeg = blockIdx.z * Kh, kend = kbeg + Kh;
    float* __restrict__ C = blockIdx.z ? C1 : C0;

    const f32x4 fz = {0.f, 0.f, 0.f, 0.f};
    f32x4 acc[4][4];
    #pragma unroll
    for (int i = 0; i < 4; ++i)
        #pragma unroll
        for (int j = 0; j < 4; ++j) acc[i][j] = fz;

    for (int k0 = kbeg; k0 < kend; k0 += 32) {
        #pragma unroll
        for (int r = 0; r < 2; ++r) {
            int c = r * 256 + tid;
            int row = c >> 2, ch = (c & 3) ^ ((row >> 1) & 3);
            async16(A + (size_t)(m0 + row) * K + k0 + ch * 8,
                    (u16*)lA + (size_t)(r * 256 + w * 64) * 8);
            async16(Bt + (size_t)(n0 + row) * K + k0 + ch * 8,
                    (u16*)lB + (size_t)(r * 256 + w * 64) * 8);
        }
        __syncthreads();
        bf16x8 af[4], bfr[4];
        #pragma unroll
        for (int i = 0; i < 4; ++i)
            af[i] = *(const bf16x8*)&lA[(wm + i * 16 + l15) * 32 + sw];
        #pragma unroll
        for (int j = 0; j < 4; ++j)
            bfr[j] = *(const bf16x8*)&lB[(wn + j * 16 + l15) * 32 + sw];
        #pragma unroll
        for (int i = 0; i < 4; ++i)
            #pragma unroll
            for (int j = 0; j < 4; ++j)
                acc[i][j] = mfma16(af[i], bfr[j], acc[i][j]);
        __syncthreads();
    }
    #pragma unroll
    for (int j = 0; j < 4; ++j) {
        int col = n0 + wn + j * 16 + l15;
        #pragma unroll
        for (int i = 0; i < 4; ++i) {
            int row = m0 + wm + i * 16 + quad * 4;
            #pragma unroll
            for (int r = 0; r < 4; ++r)
                C[(size_t)(row + r) * N + col] = acc[i][j][r];
        }
    }
}

// ------------------------------------------------------ fused QKV GEMM
__global__ __launch_bounds__(256)
void k_gemm_qkv(const u16* __restrict__ A, const u16* __restrict__ Bt,
                const float* __restrict__ bq, const float* __restrict__ bk,
                const float* __restrict__ bv,
                u16* __restrict__ qb, u16* __restrict__ kb, u16* __restrict__ vtg,
                int M, int K, float scale_q)
{
    __shared__ __align__(16) u16 lA[128 * 32];
    __shared__ __align__(16) u16 lB[128 * 32];
    const int tid = threadIdx.x;
    const int w = tid >> 6, lane = tid & 63;
    const int quad = lane >> 4, l15 = lane & 15;
    const int m0 = blockIdx.x * 128, n0 = blockIdx.y * 128;
    const int wm = (w >> 1) * 64, wn = (w & 1) * 64;
    const int sw = (quad ^ ((l15 >> 1) & 3)) * 8;
    const int sel = blockIdx.y / 6;          // 0=q 1=k 2=v
    const int cl0 = n0 - sel * 768;

    const f32x4 fz = {0.f, 0.f, 0.f, 0.f};
    f32x4 acc[4][4];
    #pragma unroll
    for (int i = 0; i < 4; ++i)
        #pragma unroll
        for (int j = 0; j < 4; ++j) acc[i][j] = fz;

    for (int k0 = 0; k0 < K; k0 += 32) {
        #pragma unroll
        for (int r = 0; r < 2; ++r) {
            int c = r * 256 + tid;
            int row = c >> 2, ch = (c & 3) ^ ((row >> 1) & 3);
            async16(A + (size_t)(m0 + row) * K + k0 + ch * 8,
                    (u16*)lA + (size_t)(r * 256 + w * 64) * 8);
            async16(Bt + (size_t)(n0 + row) * K + k0 + ch * 8,
                    (u16*)lB + (size_t)(r * 256 + w * 64) * 8);
        }
        __syncthreads();
        bf16x8 af[4], bfr[4];
        #pragma unroll
        for (int i = 0; i < 4; ++i)
            af[i] = *(const bf16x8*)&lA[(wm + i * 16 + l15) * 32 + sw];
        #pragma unroll
        for (int j = 0; j < 4; ++j)
            bfr[j] = *(const bf16x8*)&lB[(wn + j * 16 + l15) * 32 + sw];
        #pragma unroll
        for (int i = 0; i < 4; ++i)
            #pragma unroll
            for (int j = 0; j < 4; ++j)
                acc[i][j] = mfma16(af[i], bfr[j], acc[i][j]);
        __syncthreads();
    }
    const float* bias = (sel == 0) ? bq : (sel == 1) ? bk : bv;
    #pragma unroll
    for (int j = 0; j < 4; ++j) {
        int cl = cl0 + wn + j * 16 + l15;
        float bvv = bias[cl];
        #pragma unroll
        for (int i = 0; i < 4; ++i) {
            int row = m0 + wm + i * 16 + quad * 4;
            float v[4];
            #pragma unroll
            for (int r = 0; r < 4; ++r) v[r] = acc[i][j][r] + bvv;
            if (sel == 0) {
                #pragma unroll
                for (int r = 0; r < 4; ++r)
                    qb[(size_t)(row + r) * 768 + cl] = f2bf(v[r] * scale_q);
            } else if (sel == 1) {
                #pragma unroll
                for (int r = 0; r < 4; ++r)
                    kb[(size_t)(row + r) * 768 + cl] = f2bf(v[r]);
            } else {
                uint2 d;
                d.x = pack_bf2(v[0], v[1]);
                d.y = pack_bf2(v[2], v[3]);
                *(uint2*)(vtg + (size_t)cl * M + row) = d;
            }
        }
    }
}

// ------------------------------------------------------------- attention
// Fixed-max flash attention, S^T = K@Q^T trick (lane owns one q-row).
// 4 waves = (wq: 2 q-halves) x (wk: 2 key-halves). Wave: 64 q-rows (4 sets),
// 32 keys/iter (its half of a 64-key tile), kt step 64. K/V fragments loaded
// DIRECTLY from global (L2-resident, 64B segments) — no LDS staging, no
// barriers in the K-loop. P roundtrip per-wave in LDS (stride 36). Partial
// (O,l) of key-half 1 combined with half 0 through LDS at the end.
__global__ __launch_bounds__(256, 3)
void k_attention(const u16* __restrict__ Q, const u16* __restrict__ Kb,
                 const u16* __restrict__ Vt, u16* __restrict__ ctx,
                 int S, int D, int H, int M)
{
    __shared__ __align__(16) u16 lP[4][16 * 36];
    __shared__ __align__(16) u16 lO[2 * 64 * 66];
    __shared__ float lL[2][64];
    const int qt = blockIdx.x, bh = blockIdx.y;
    const int b = bh / H, h = bh % H;
    const int tid = threadIdx.x, w = tid >> 6, lane = tid & 63;
    const int wq = w & 1, wk = w >> 1;
    const int quad = lane >> 4, l15 = lane & 15;
    const size_t bS = (size_t)b * S;
    const int q0 = qt * 128 + wq * 64;

    // persistent Q B-frags: B[k=dk][n=qrow], lane: qrow=set*16+l15, dk=kc*32+quad*8
    bf16x8 qf[4][2];
    #pragma unroll
    for (int set = 0; set < 4; ++set)
        #pragma unroll
        for (int kc = 0; kc < 2; ++kc)
            qf[set][kc] = *(const bf16x8*)(Q + (bS + q0 + set * 16 + l15) * D
                                           + (size_t)h * 64 + kc * 32 + quad * 8);

    const f32x4 fz = {0.f, 0.f, 0.f, 0.f};
    f32x4 O[4][4];
    #pragma unroll
    for (int s = 0; s < 4; ++s)
        #pragma unroll
        for (int j = 0; j < 4; ++j) O[s][j] = fz;
    float l_[4] = {0.f, 0.f, 0.f, 0.f};
    u16* myP = lP[w];

    // K rows (A-frag): key = kt + wk*32 + ks*16 + l15, dk = kc*32 + quad*8
    const u16* ka0 = Kb + (bS + wk * 32 + l15) * D + (size_t)h * 64 + quad * 8;
    const u16* ka1 = ka0 + (size_t)16 * D;
    // V rows (B-frag, from vtg[dk][token]): dk = dj*16+l15, key = kt + wk*32 + quad*8
    const u16* vr0 = Vt + ((size_t)h * 64 + l15) * M + bS + wk * 32 + quad * 8;
    const u16* vr1 = vr0 + (size_t)16 * M;
    const u16* vr2 = vr1 + (size_t)16 * M;
    const u16* vr3 = vr2 + (size_t)16 * M;

    for (int kt = 0; kt < S; kt += 64) {
        bf16x8 ka[2][2], vf[4];
        ka[0][0] = *(const bf16x8*)(ka0);
        ka[0][1] = *(const bf16x8*)(ka0 + 32);
        ka[1][0] = *(const bf16x8*)(ka1);
        ka[1][1] = *(const bf16x8*)(ka1 + 32);
        vf[0] = *(const bf16x8*)(vr0);
        vf[1] = *(const bf16x8*)(vr1);
        vf[2] = *(const bf16x8*)(vr2);
        vf[3] = *(const bf16x8*)(vr3);
        ka0 += (size_t)64 * D; ka1 += (size_t)64 * D;
        vr0 += 64; vr1 += 64; vr2 += 64; vr3 += 64;

        #pragma unroll
        for (int set = 0; set < 4; ++set) {
            f32x4 sc0 = fz, sc1 = fz;
            sc0 = mfma16(ka[0][0], qf[set][0], sc0);
            sc0 = mfma16(ka[0][1], qf[set][1], sc0);
            sc1 = mfma16(ka[1][0], qf[set][0], sc1);
            sc1 = mfma16(ka[1][1], qf[set][1], sc1);
            float p0[4], p1[4];
            float rs = 0.f;
            #pragma unroll
            for (int r = 0; r < 4; ++r) {
                p0[r] = __builtin_amdgcn_exp2f(sc0[r]);
                p1[r] = __builtin_amdgcn_exp2f(sc1[r]);
                rs += p0[r] + p1[r];
            }
            l_[set] += rs;
            uint2 d0, d1;
            d0.x = pack_bf2(p0[0], p0[1]); d0.y = pack_bf2(p0[2], p0[3]);
            d1.x = pack_bf2(p1[0], p1[1]); d1.y = pack_bf2(p1[2], p1[3]);
            // P row = qrow l15, keys ks*16 + quad*4 + r (32 keys this iter)
            *(uint2*)&myP[l15 * 36 + quad * 4] = d0;
            *(uint2*)&myP[l15 * 36 + 16 + quad * 4] = d1;
            // A-frag read: m=l15(qrow), k=quad*8+j; wave-local, DS in-order
            bf16x8 pa = *(const bf16x8*)&myP[l15 * 36 + quad * 8];
            #pragma unroll
            for (int dj = 0; dj < 4; ++dj)
                O[set][dj] = mfma16(pa, vf[dj], O[set][dj]);
        }
    }

    // per-q-row l: reduce across quads (lane owns qrow=l15 of each set)
    float lred[4];
    #pragma unroll
    for (int set = 0; set < 4; ++set) {
        float lt = l_[set];
        lt += __shfl_xor(lt, 16, 64);
        lt += __shfl_xor(lt, 32, 64);
        lred[set] = lt;
    }
    // combine key-halves through LDS (fixed-max: plain addition)
    if (wk == 1) {
        #pragma unroll
        for (int set = 0; set < 4; ++set) {
            #pragma unroll
            for (int dj = 0; dj < 4; ++dj)
                #pragma unroll
                for (int r = 0; r < 4; ++r)
                    lO[(wq * 64 + set * 16 + quad * 4 + r) * 66 + dj * 16 + l15]
                        = f2bf(O[set][dj][r]);
            if (lane < 16) lL[wq][set * 16 + lane] = lred[set];
        }
    }
    __syncthreads();
    if (wk == 0) {
        #pragma unroll
        for (int set = 0; set < 4; ++set) {
            float ltot = lred[set] + lL[wq][set * 16 + l15];
            float rl[4];
            #pragma unroll
            for (int r = 0; r < 4; ++r)
                rl[r] = 1.f / __shfl(ltot, quad * 4 + r, 64);
            #pragma unroll
            for (int dj = 0; dj < 4; ++dj)
                #pragma unroll
                for (int r = 0; r < 4; ++r) {
                    float o = O[set][dj][r]
                        + bf2f(lO[(wq * 64 + set * 16 + quad * 4 + r) * 66 + dj * 16 + l15]);
                    ctx[(bS + q0 + set * 16 + quad * 4 + r) * D
                        + (size_t)h * 64 + dj * 16 + l15] = f2bf(o * rl[r]);
                }
        }
    }
}

// -------------------------------------------- layernorm over sum of parts
// t = p0 + p1 + resid + bias[col];  out = a*((t-m)/(std_ddof1+eps)) + g
__global__ __launch_bounds__(256)
void k_layernorm2(const float* __restrict__ p0, const float* __restrict__ p1,
                  const float* __restrict__ resid, const float* __restrict__ bias,
                  const float* __restrict__ a, const float* __restrict__ g,
                  float* __restrict__ outf, u16* __restrict__ outb, int D)
{
    const int row = blockIdx.x, tid = threadIdx.x;
    const size_t base = (size_t)row * D;
    float v[3];
    float s = 0.f, sq = 0.f;
    #pragma unroll
    for (int i = 0; i < 3; ++i) {
        int c = tid + i * 256;
        float x = p0[base + c] + p1[base + c] + resid[base + c] + bias[c];
        v[i] = x; s += x; sq += x * x;
    }
    #pragma unroll
    for (int off = 32; off >= 1; off >>= 1) {
        s += __shfl_xor(s, off, 64);
        sq += __shfl_xor(sq, off, 64);
    }
    __shared__ float red[8];
    const int w = tid >> 6;
    if ((tid & 63) == 0) { red[w] = s; red[4 + w] = sq; }
    __syncthreads();
    s = red[0] + red[1] + red[2] + red[3];
    sq = red[4] + red[5] + red[6] + red[7];
    float mean = s / D;
    float var = fmaxf((sq - s * mean) / (D - 1), 0.f);
    float denom = sqrtf(var) + 1e-5f;
    float av = a[0], gv = g[0];
    #pragma unroll
    for (int i = 0; i < 3; ++i) {
        float y = av * ((v[i] - mean) / denom) + gv;
        if (outf) outf[base + tid + i * 256] = y;
        if (outb) outb[base + tid + i * 256] = f2bf(y);
    }
}

// ---------------------------------------------------------------- launch
extern "C" void kernel_launch(void* const* d_in, const int* in_sizes, int n_in,
                              void* d_out, int out_size, void* d_ws, size_t ws_size,
                              hipStream_t stream)
{
    constexpr int B = 2, S = 4096, D = 768, H = 12, F = 3072;
    constexpr int M = B * S;
    const float SCALE_Q = 1.4426950408889634f / 8.0f;  // log2(e)/sqrt(dk)
    const float* x  = (const float*)d_in[0];
    const float* wq = (const float*)d_in[1];
    const float* bq = (const float*)d_in[2];
    const float* wk = (const float*)d_in[3];
    const float* bk = (const float*)d_in[4];
    const float* wv = (const float*)d_in[5];
    const float* bv = (const float*)d_in[6];
    const float* wo = (const float*)d_in[7];
    const float* bo = (const float*)d_in[8];
    const float* w1 = (const float*)d_in[9];
    const float* b1 = (const float*)d_in[10];
    const float* w2 = (const float*)d_in[11];
    const float* b2 = (const float*)d_in[12];
    const float* a1 = (const float*)d_in[13];
    const float* g1 = (const float*)d_in[14];
    const float* a2 = (const float*)d_in[15];
    const float* g2 = (const float*)d_in[16];

    char* ws = (char*)d_ws;
    size_t off = 0;
    auto alloc = [&](size_t bytes) {
        void* p = ws + off;
        off = (off + bytes + 255) & ~(size_t)255;
        return p;
    };
    u16*   xb    = (u16*)alloc((size_t)M * D * 2);
    u16*   wqkvt = (u16*)alloc((size_t)3 * D * D * 2);
    u16*   wot   = (u16*)alloc((size_t)D * D * 2);
    u16*   w1t   = (u16*)alloc((size_t)D * F * 2);
    u16*   w2t   = (u16*)alloc((size_t)D * F * 2);
    u16*   qb    = (u16*)alloc((size_t)M * D * 2);
    u16*   kb    = (u16*)alloc((size_t)M * D * 2);
    u16*   vtg   = (u16*)alloc((size_t)M * D * 2);  // V transposed: [D][M]
    u16*   ctxb  = (u16*)alloc((size_t)M * D * 2);
    float* x1f   = (float*)alloc((size_t)M * D * 4);
    u16*   x1b   = (u16*)alloc((size_t)M * D * 2);
    u16*   ff1b  = (u16*)alloc((size_t)M * F * 2);

    // split-K fp32 partial overlays (each M*D*4 = two bf16 M*D buffers):
    float* p0a = (float*)qb;     // WO partial 0 over qb+kb   (dead after attn)
    float* p1a = (float*)ff1b;   // WO partial 1 over ff1b    (not yet live)
    float* p0b = (float*)qb;     // FF2 partial 0 over qb+kb
    float* p1b = (float*)vtg;    // FF2 partial 1 over vtg+ctxb (dead after WO)

    // fused conversion + weight transposes (1 launch)
    k_prep<<<6144 + 6912, 256, 0, stream>>>(x, xb, wq, wk, wv, wo, w1, w2,
                                            wqkvt, wot, w1t, w2t);

    // fused QKV projection (q scaled, v written transposed)
    k_gemm_qkv<<<dim3(M / 128, 3 * D / 128), 256, 0, stream>>>(
        xb, wqkvt, bq, bk, bv, qb, kb, vtg, M, D, SCALE_Q);

    k_attention<<<dim3(S / 128, B * H), 256, 0, stream>>>(qb, kb, vtg, ctxb, S, D, H, M);

    // WO projection, split-K=2 -> partials; LN1 fuses sum + bo + residual(x)
    k_gemm_part<<<dim3(M / 128, D / 128, 2), 256, 0, stream>>>(
        ctxb, wot, p0a, p1a, M, D, D, D / 2);
    k_layernorm2<<<M, 256, 0, stream>>>(p0a, p1a, x, bo, a1, g1, x1f, x1b, D);

    // FF1 (relu) -> ff1b
    k_gemm<true><<<dim3(M / 128, F / 128), 256, 0, stream>>>(
        x1b, w1t, b1, ff1b, M, F, D);
    // FF2 split-K=2 -> partials; LN2 fuses sum + b2 + residual(x1f) -> d_out
    k_gemm_part<<<dim3(M / 128, D / 128, 2), 256, 0, stream>>>(
        ff1b, w2t, p0b, p1b, M, D, F, F / 2);
    k_layernorm2<<<M, 256, 0, stream>>>(p0b, p1b, x1f, b2, a2, g2, (float*)d_out, nullptr, D);

    (void)in_sizes; (void)n_in; (void)out_size; (void)ws_size;
}

// Round 6
// 504.440 us; speedup vs baseline: 1.1972x; 1.1972x over previous
//
#include <hip/hip_runtime.h>
#include <hip/hip_bf16.h>
#include <cstdint>
#include <cstddef>

typedef unsigned short u16;
typedef __attribute__((ext_vector_type(8))) __bf16 bf16x8;
typedef __attribute__((ext_vector_type(4))) float f32x4;

#define AS1 __attribute__((address_space(1)))
#define AS3 __attribute__((address_space(3)))

__device__ __forceinline__ u16 f2bf(float f) {
    union { float f; uint32_t u; } v; v.f = f;
    uint32_t r = (v.u + 0x7FFFu + ((v.u >> 16) & 1u)) >> 16;
    return (u16)r;
}

__device__ __forceinline__ float bf2f(u16 b) {
    union { uint32_t u; float f; } v; v.u = ((uint32_t)b) << 16;
    return v.f;
}

__device__ __forceinline__ uint32_t pack_bf2(float lo, float hi) {
    __hip_bfloat162 p = __float22bfloat162_rn(float2{lo, hi});
    union { __hip_bfloat162 b; uint32_t u; } v; v.b = p;
    return v.u;
}

__device__ __forceinline__ f32x4 mfma16(bf16x8 a, bf16x8 b, f32x4 c) {
    return __builtin_amdgcn_mfma_f32_16x16x32_bf16(a, b, c, 0, 0, 0);
}

// async global->LDS, 16B per lane; lane i lands at base + i*16.
__device__ __forceinline__ void async16(const u16* g, u16* lds_uniform_base) {
    __builtin_amdgcn_global_load_lds((const AS1 void*)g, (AS3 void*)lds_uniform_base, 16, 0, 0);
}

// ------------------------------------------------------------ fused prep
__global__ __launch_bounds__(256)
void k_prep(const float* __restrict__ x, u16* __restrict__ xb,
            const float* __restrict__ wq, const float* __restrict__ wk,
            const float* __restrict__ wv, const float* __restrict__ wo,
            const float* __restrict__ w1, const float* __restrict__ w2,
            u16* __restrict__ wqkvt, u16* __restrict__ wot,
            u16* __restrict__ w1t, u16* __restrict__ w2t)
{
    int bx = blockIdx.x;
    if (bx < 6144) {
        int i = (bx * 256 + threadIdx.x) * 4;
        float4 f = *(const float4*)(x + i);
        xb[i + 0] = f2bf(f.x); xb[i + 1] = f2bf(f.y);
        xb[i + 2] = f2bf(f.z); xb[i + 3] = f2bf(f.w);
        return;
    }
    int t = bx - 6144;
    const float* in; u16* out; int R, C;
    if (t < 2304) {
        int m = t / 576; t -= m * 576;
        R = 768; C = 768;
        in = (m == 0) ? wq : (m == 1) ? wk : (m == 2) ? wv : wo;
        out = (m < 3) ? wqkvt + (size_t)m * 768 * 768 : wot;
    } else if (t < 4608) {
        t -= 2304; in = w1; out = w1t; R = 768; C = 3072;
    } else {
        t -= 4608; in = w2; out = w2t; R = 3072; C = 768;
    }
    int tilesX = C >> 5;
    int c0 = (t % tilesX) * 32, r0 = (t / tilesX) * 32;
    __shared__ float tile[32][33];
    int tx = threadIdx.x & 31, ty = threadIdx.x >> 5;
    #pragma unroll
    for (int i = ty; i < 32; i += 8)
        tile[i][tx] = in[(size_t)(r0 + i) * C + c0 + tx];
    __syncthreads();
    #pragma unroll
    for (int i = ty; i < 32; i += 8)
        out[(size_t)(c0 + i) * R + r0 + tx] = f2bf(tile[tx][i]);
}

// ---------------------------------------------------------------- GEMM
template <bool RELU>
__global__ __launch_bounds__(256)
void k_gemm(const u16* __restrict__ A, const u16* __restrict__ Bt,
            const float* __restrict__ bias, u16* __restrict__ Cb,
            int M, int N, int K)
{
    __shared__ __align__(16) u16 lA[128 * 32];
    __shared__ __align__(16) u16 lB[128 * 32];
    const int tid = threadIdx.x;
    const int w = tid >> 6, lane = tid & 63;
    const int quad = lane >> 4, l15 = lane & 15;
    const int m0 = blockIdx.x * 128, n0 = blockIdx.y * 128;
    const int wm = (w >> 1) * 64, wn = (w & 1) * 64;
    const int sw = (quad ^ ((l15 >> 1) & 3)) * 8;

    const f32x4 fz = {0.f, 0.f, 0.f, 0.f};
    f32x4 acc[4][4];
    #pragma unroll
    for (int i = 0; i < 4; ++i)
        #pragma unroll
        for (int j = 0; j < 4; ++j) acc[i][j] = fz;

    for (int k0 = 0; k0 < K; k0 += 32) {
        #pragma unroll
        for (int r = 0; r < 2; ++r) {
            int c = r * 256 + tid;
            int row = c >> 2, ch = (c & 3) ^ ((row >> 1) & 3);
            async16(A + (size_t)(m0 + row) * K + k0 + ch * 8,
                    (u16*)lA + (size_t)(r * 256 + w * 64) * 8);
            async16(Bt + (size_t)(n0 + row) * K + k0 + ch * 8,
                    (u16*)lB + (size_t)(r * 256 + w * 64) * 8);
        }
        __syncthreads();
        bf16x8 af[4], bfr[4];
        #pragma unroll
        for (int i = 0; i < 4; ++i)
            af[i] = *(const bf16x8*)&lA[(wm + i * 16 + l15) * 32 + sw];
        #pragma unroll
        for (int j = 0; j < 4; ++j)
            bfr[j] = *(const bf16x8*)&lB[(wn + j * 16 + l15) * 32 + sw];
        #pragma unroll
        for (int i = 0; i < 4; ++i)
            #pragma unroll
            for (int j = 0; j < 4; ++j)
                acc[i][j] = mfma16(af[i], bfr[j], acc[i][j]);
        __syncthreads();
    }
    #pragma unroll
    for (int j = 0; j < 4; ++j) {
        int col = n0 + wn + j * 16 + l15;
        float bv = bias[col];
        #pragma unroll
        for (int i = 0; i < 4; ++i) {
            int row = m0 + wm + i * 16 + quad * 4;
            #pragma unroll
            for (int r = 0; r < 4; ++r) {
                float t = acc[i][j][r] + bv;
                if (RELU) t = fmaxf(t, 0.f);
                Cb[(size_t)(row + r) * N + col] = f2bf(t);
            }
        }
    }
}

// ------------------------------------------------- split-K partial GEMM
__global__ __launch_bounds__(256)
void k_gemm_part(const u16* __restrict__ A, const u16* __restrict__ Bt,
                 float* __restrict__ C0, float* __restrict__ C1,
                 int M, int N, int K, int Kh)
{
    __shared__ __align__(16) u16 lA[128 * 32];
    __shared__ __align__(16) u16 lB[128 * 32];
    const int tid = threadIdx.x;
    const int w = tid >> 6, lane = tid & 63;
    const int quad = lane >> 4, l15 = lane & 15;
    const int m0 = blockIdx.x * 128, n0 = blockIdx.y * 128;
    const int wm = (w >> 1) * 64, wn = (w & 1) * 64;
    const int sw = (quad ^ ((l15 >> 1) & 3)) * 8;
    const int kbeg = blockIdx.z * Kh, kend = kbeg + Kh;
    float* __restrict__ C = blockIdx.z ? C1 : C0;

    const f32x4 fz = {0.f, 0.f, 0.f, 0.f};
    f32x4 acc[4][4];
    #pragma unroll
    for (int i = 0; i < 4; ++i)
        #pragma unroll
        for (int j = 0; j < 4; ++j) acc[i][j] = fz;

    for (int k0 = kbeg; k0 < kend; k0 += 32) {
        #pragma unroll
        for (int r = 0; r < 2; ++r) {
            int c = r * 256 + tid;
            int row = c >> 2, ch = (c & 3) ^ ((row >> 1) & 3);
            async16(A + (size_t)(m0 + row) * K + k0 + ch * 8,
                    (u16*)lA + (size_t)(r * 256 + w * 64) * 8);
            async16(Bt + (size_t)(n0 + row) * K + k0 + ch * 8,
                    (u16*)lB + (size_t)(r * 256 + w * 64) * 8);
        }
        __syncthreads();
        bf16x8 af[4], bfr[4];
        #pragma unroll
        for (int i = 0; i < 4; ++i)
            af[i] = *(const bf16x8*)&lA[(wm + i * 16 + l15) * 32 + sw];
        #pragma unroll
        for (int j = 0; j < 4; ++j)
            bfr[j] = *(const bf16x8*)&lB[(wn + j * 16 + l15) * 32 + sw];
        #pragma unroll
        for (int i = 0; i < 4; ++i)
            #pragma unroll
            for (int j = 0; j < 4; ++j)
                acc[i][j] = mfma16(af[i], bfr[j], acc[i][j]);
        __syncthreads();
    }
    #pragma unroll
    for (int j = 0; j < 4; ++j) {
        int col = n0 + wn + j * 16 + l15;
        #pragma unroll
        for (int i = 0; i < 4; ++i) {
            int row = m0 + wm + i * 16 + quad * 4;
            #pragma unroll
            for (int r = 0; r < 4; ++r)
                C[(size_t)(row + r) * N + col] = acc[i][j][r];
        }
    }
}

// ------------------------------------------------------ fused QKV GEMM
// sel==2 (V): output written TRANSPOSED to vtg[D][M] via per-wave LDS
// transpose -> 16B contiguous global stores (instead of 8B scatter).
__global__ __launch_bounds__(256)
void k_gemm_qkv(const u16* __restrict__ A, const u16* __restrict__ Bt,
                const float* __restrict__ bq, const float* __restrict__ bk,
                const float* __restrict__ bv,
                u16* __restrict__ qb, u16* __restrict__ kb, u16* __restrict__ vtg,
                int M, int K, float scale_q)
{
    __shared__ __align__(16) u16 qsm[4 * 64 * 72];   // staging (8192) | V-transpose
    u16* lA = qsm;
    u16* lB = qsm + 4096;
    const int tid = threadIdx.x;
    const int w = tid >> 6, lane = tid & 63;
    const int quad = lane >> 4, l15 = lane & 15;
    const int m0 = blockIdx.x * 128, n0 = blockIdx.y * 128;
    const int wm = (w >> 1) * 64, wn = (w & 1) * 64;
    const int sw = (quad ^ ((l15 >> 1) & 3)) * 8;
    const int sel = blockIdx.y / 6;          // 0=q 1=k 2=v
    const int cl0 = n0 - sel * 768;

    const f32x4 fz = {0.f, 0.f, 0.f, 0.f};
    f32x4 acc[4][4];
    #pragma unroll
    for (int i = 0; i < 4; ++i)
        #pragma unroll
        for (int j = 0; j < 4; ++j) acc[i][j] = fz;

    for (int k0 = 0; k0 < K; k0 += 32) {
        #pragma unroll
        for (int r = 0; r < 2; ++r) {
            int c = r * 256 + tid;
            int row = c >> 2, ch = (c & 3) ^ ((row >> 1) & 3);
            async16(A + (size_t)(m0 + row) * K + k0 + ch * 8,
                    lA + (size_t)(r * 256 + w * 64) * 8);
            async16(Bt + (size_t)(n0 + row) * K + k0 + ch * 8,
                    lB + (size_t)(r * 256 + w * 64) * 8);
        }
        __syncthreads();
        bf16x8 af[4], bfr[4];
        #pragma unroll
        for (int i = 0; i < 4; ++i)
            af[i] = *(const bf16x8*)&lA[(wm + i * 16 + l15) * 32 + sw];
        #pragma unroll
        for (int j = 0; j < 4; ++j)
            bfr[j] = *(const bf16x8*)&lB[(wn + j * 16 + l15) * 32 + sw];
        #pragma unroll
        for (int i = 0; i < 4; ++i)
            #pragma unroll
            for (int j = 0; j < 4; ++j)
                acc[i][j] = mfma16(af[i], bfr[j], acc[i][j]);
        __syncthreads();
    }
    const float* bias = (sel == 0) ? bq : (sel == 1) ? bk : bv;
    if (sel < 2) {
        u16* out = (sel == 0) ? qb : kb;
        float sc = (sel == 0) ? scale_q : 1.f;
        #pragma unroll
        for (int j = 0; j < 4; ++j) {
            int cl = cl0 + wn + j * 16 + l15;
            float bvv = bias[cl];
            #pragma unroll
            for (int i = 0; i < 4; ++i) {
                int row = m0 + wm + i * 16 + quad * 4;
                #pragma unroll
                for (int r = 0; r < 4; ++r)
                    out[(size_t)(row + r) * 768 + cl] = f2bf((acc[i][j][r] + bvv) * sc);
            }
        }
    } else {
        // per-wave 64x64 transpose through LDS (stride 72, 16B-aligned rows)
        u16* lT = qsm + w * 4608;
        #pragma unroll
        for (int j = 0; j < 4; ++j) {
            float bvv = bias[cl0 + wn + j * 16 + l15];
            #pragma unroll
            for (int i = 0; i < 4; ++i)
                #pragma unroll
                for (int r = 0; r < 4; ++r)
                    lT[(j * 16 + l15) * 72 + i * 16 + quad * 4 + r]
                        = f2bf(acc[i][j][r] + bvv);
        }
        // wave-local DS ordering: reads below see the writes above
        int gcol = cl0 + wn + lane;
        u16* gdst = vtg + (size_t)gcol * M + m0 + wm;
        #pragma unroll
        for (int kk = 0; kk < 8; ++kk) {
            bf16x8 v = *(const bf16x8*)&lT[lane * 72 + kk * 8];
            *(bf16x8*)(gdst + kk * 8) = v;
        }
    }
}

// ------------------------------------------------------------- attention
// Fixed-max flash attention, S^T = K@Q^T trick (lane owns one q-row, no
// shuffles in K-loop). 4 waves = (wq: 2 q-halves) x (wk: 2 key-halves).
// 64-key tiles, DOUBLE-BUFFERED K/V LDS staging with prefetch-before-compute
// (one barrier/iter; prefetch flies during compute). P double-buffered per
// wave so the 4 sets' score/exp/PV chains can interleave.
__global__ __launch_bounds__(256, 3)
void k_attention(const u16* __restrict__ Q, const u16* __restrict__ Kb,
                 const u16* __restrict__ Vt, u16* __restrict__ ctx,
                 int S, int D, int H, int M)
{
    __shared__ __align__(16) u16 sKV[16384];  // K0|K1|V0|V1, 4096 u16 each
    __shared__ __align__(16) u16 sP[4608];    // 4 waves x 2 bufs x 16 x 36
    __shared__ float sL[2][64];
    const int qt = blockIdx.x, bh = blockIdx.y;
    const int b = bh / H, h = bh % H;
    const int tid = threadIdx.x, w = tid >> 6, lane = tid & 63;
    const int wq = w & 1, wk = w >> 1;
    const int quad = lane >> 4, l15 = lane & 15;
    const int sw = (quad ^ ((l15 >> 1) & 3)) * 8;
    const size_t bS = (size_t)b * S;
    const int q0 = qt * 128 + wq * 64;

    // persistent Q B-frags: qrow = set*16+l15, dk = kc*32+quad*8
    bf16x8 qf[4][2];
    #pragma unroll
    for (int set = 0; set < 4; ++set)
        #pragma unroll
        for (int kc = 0; kc < 2; ++kc)
            qf[set][kc] = *(const bf16x8*)(Q + (bS + q0 + set * 16 + l15) * D
                                           + (size_t)h * 64 + kc * 32 + quad * 8);

    const f32x4 fz = {0.f, 0.f, 0.f, 0.f};
    f32x4 O[4][4];
    #pragma unroll
    for (int s = 0; s < 4; ++s)
        #pragma unroll
        for (int j = 0; j < 4; ++j) O[s][j] = fz;
    float l_[4] = {0.f, 0.f, 0.f, 0.f};
    u16* myP = sP + w * 1152;

    const u16* kbase = Kb + bS * D + (size_t)h * 64;
    const u16* vbase = Vt + (size_t)h * 64 * M + bS;

    // per-thread staging sources (2 K-chunks, 2 V-chunks; 64x64 tiles)
    const u16* gk[2]; const u16* gv[2];
    #pragma unroll
    for (int i = 0; i < 2; ++i) {
        int c = i * 256 + tid;
        int kc = c >> 8;
        int krow = (c >> 2) & 63, kch = (c & 3) ^ ((krow >> 1) & 3);
        gk[i] = kbase + (size_t)krow * D + kc * 32 + kch * 8;
        int dk = (c >> 2) & 63, vch = (c & 3) ^ ((dk >> 1) & 3);
        gv[i] = vbase + (size_t)dk * M + kc * 32 + vch * 8;
    }
    const int dslot = (w * 64) * 8;  // wave-uniform LDS chunk base (u16)

    // prologue: stage tile 0 into buffer 0
    #pragma unroll
    for (int i = 0; i < 2; ++i) {
        async16(gk[i], sKV + i * 2048 + dslot);
        async16(gv[i], sKV + 8192 + i * 2048 + dslot);
        gk[i] += (size_t)64 * D;
        gv[i] += 64;
    }

    const int T = S >> 6;
    for (int t = 0; t < T; ++t) {
        __syncthreads();  // buf[t&1] staged; all prior LDS reads drained
        if (t + 1 < T) {
            int nb = (t + 1) & 1;
            #pragma unroll
            for (int i = 0; i < 2; ++i) {
                async16(gk[i], sKV + nb * 4096 + i * 2048 + dslot);
                async16(gv[i], sKV + 8192 + nb * 4096 + i * 2048 + dslot);
                gk[i] += (size_t)64 * D;
                gv[i] += 64;
            }
        }
        const u16* lKb = sKV + (t & 1) * 4096;
        const u16* lVb = sKV + 8192 + (t & 1) * 4096;

        // wave's 32 keys: wk*32 .. +31
        bf16x8 ka[2][2], vf[4];
        #pragma unroll
        for (int ks = 0; ks < 2; ++ks)
            #pragma unroll
            for (int kc = 0; kc < 2; ++kc)
                ka[ks][kc] = *(const bf16x8*)
                    &lKb[kc * 2048 + (wk * 32 + ks * 16 + l15) * 32 + sw];
        #pragma unroll
        for (int dj = 0; dj < 4; ++dj)
            vf[dj] = *(const bf16x8*)
                &lVb[wk * 2048 + (dj * 16 + l15) * 32 + sw];

        #pragma unroll
        for (int set = 0; set < 4; ++set) {
            f32x4 sc0 = fz, sc1 = fz;
            sc0 = mfma16(ka[0][0], qf[set][0], sc0);
            sc0 = mfma16(ka[0][1], qf[set][1], sc0);
            sc1 = mfma16(ka[1][0], qf[set][0], sc1);
            sc1 = mfma16(ka[1][1], qf[set][1], sc1);
            float p0[4], p1[4];
            float rs = 0.f;
            #pragma unroll
            for (int r = 0; r < 4; ++r) {
                p0[r] = __builtin_amdgcn_exp2f(sc0[r]);
                p1[r] = __builtin_amdgcn_exp2f(sc1[r]);
                rs += p0[r] + p1[r];
            }
            l_[set] += rs;
            uint2 d0, d1;
            d0.x = pack_bf2(p0[0], p0[1]); d0.y = pack_bf2(p0[2], p0[3]);
            d1.x = pack_bf2(p1[0], p1[1]); d1.y = pack_bf2(p1[2], p1[3]);
            u16* Pb = myP + (set & 1) * 576;
            *(uint2*)&Pb[l15 * 36 + quad * 4] = d0;
            *(uint2*)&Pb[l15 * 36 + 16 + quad * 4] = d1;
            bf16x8 pa = *(const bf16x8*)&Pb[l15 * 36 + quad * 8];
            #pragma unroll
            for (int dj = 0; dj < 4; ++dj)
                O[set][dj] = mfma16(pa, vf[dj], O[set][dj]);
        }
    }

    // reduce l across quads (lane owns qrow=l15 of each set)
    float lred[4];
    #pragma unroll
    for (int set = 0; set < 4; ++set) {
        float lt = l_[set];
        lt += __shfl_xor(lt, 16, 64);
        lt += __shfl_xor(lt, 32, 64);
        lred[set] = lt;
    }
    __syncthreads();  // all compute reads drained; safe to alias staging LDS
    u16* lO = sKV;    // [qrow128][dk64+2pad] bf16 = 8448 u16
    if (wk == 1) {
        #pragma unroll
        for (int set = 0; set < 4; ++set) {
            #pragma unroll
            for (int dj = 0; dj < 4; ++dj)
                #pragma unroll
                for (int r = 0; r < 4; ++r)
                    lO[(wq * 64 + set * 16 + quad * 4 + r) * 66 + dj * 16 + l15]
                        = f2bf(O[set][dj][r]);
            if (lane < 16) sL[wq][set * 16 + lane] = lred[set];
        }
    }
    __syncthreads();
    if (wk == 0) {
        #pragma unroll
        for (int set = 0; set < 4; ++set) {
            float ltot = lred[set] + sL[wq][set * 16 + l15];
            float rl[4];
            #pragma unroll
            for (int r = 0; r < 4; ++r)
                rl[r] = 1.f / __shfl(ltot, quad * 4 + r, 64);
            #pragma unroll
            for (int dj = 0; dj < 4; ++dj)
                #pragma unroll
                for (int r = 0; r < 4; ++r) {
                    float o = O[set][dj][r]
                        + bf2f(lO[(wq * 64 + set * 16 + quad * 4 + r) * 66 + dj * 16 + l15]);
                    ctx[(bS + q0 + set * 16 + quad * 4 + r) * D
                        + (size_t)h * 64 + dj * 16 + l15] = f2bf(o * rl[r]);
                }
        }
    }
}

// -------------------------------------------- layernorm over sum of parts
__global__ __launch_bounds__(256)
void k_layernorm2(const float* __restrict__ p0, const float* __restrict__ p1,
                  const float* __restrict__ resid, const float* __restrict__ bias,
                  const float* __restrict__ a, const float* __restrict__ g,
                  float* __restrict__ outf, u16* __restrict__ outb, int D)
{
    const int row = blockIdx.x, tid = threadIdx.x;
    const size_t base = (size_t)row * D;
    float v[3];
    float s = 0.f, sq = 0.f;
    #pragma unroll
    for (int i = 0; i < 3; ++i) {
        int c = tid + i * 256;
        float x = p0[base + c] + p1[base + c] + resid[base + c] + bias[c];
        v[i] = x; s += x; sq += x * x;
    }
    #pragma unroll
    for (int off = 32; off >= 1; off >>= 1) {
        s += __shfl_xor(s, off, 64);
        sq += __shfl_xor(sq, off, 64);
    }
    __shared__ float red[8];
    const int w = tid >> 6;
    if ((tid & 63) == 0) { red[w] = s; red[4 + w] = sq; }
    __syncthreads();
    s = red[0] + red[1] + red[2] + red[3];
    sq = red[4] + red[5] + red[6] + red[7];
    float mean = s / D;
    float var = fmaxf((sq - s * mean) / (D - 1), 0.f);
    float denom = sqrtf(var) + 1e-5f;
    float av = a[0], gv = g[0];
    #pragma unroll
    for (int i = 0; i < 3; ++i) {
        float y = av * ((v[i] - mean) / denom) + gv;
        if (outf) outf[base + tid + i * 256] = y;
        if (outb) outb[base + tid + i * 256] = f2bf(y);
    }
}

// ---------------------------------------------------------------- launch
extern "C" void kernel_launch(void* const* d_in, const int* in_sizes, int n_in,
                              void* d_out, int out_size, void* d_ws, size_t ws_size,
                              hipStream_t stream)
{
    constexpr int B = 2, S = 4096, D = 768, H = 12, F = 3072;
    constexpr int M = B * S;
    const float SCALE_Q = 1.4426950408889634f / 8.0f;  // log2(e)/sqrt(dk)
    const float* x  = (const float*)d_in[0];
    const float* wq = (const float*)d_in[1];
    const float* bq = (const float*)d_in[2];
    const float* wk = (const float*)d_in[3];
    const float* bk = (const float*)d_in[4];
    const float* wv = (const float*)d_in[5];
    const float* bv = (const float*)d_in[6];
    const float* wo = (const float*)d_in[7];
    const float* bo = (const float*)d_in[8];
    const float* w1 = (const float*)d_in[9];
    const float* b1 = (const float*)d_in[10];
    const float* w2 = (const float*)d_in[11];
    const float* b2 = (const float*)d_in[12];
    const float* a1 = (const float*)d_in[13];
    const float* g1 = (const float*)d_in[14];
    const float* a2 = (const float*)d_in[15];
    const float* g2 = (const float*)d_in[16];

    char* ws = (char*)d_ws;
    size_t off = 0;
    auto alloc = [&](size_t bytes) {
        void* p = ws + off;
        off = (off + bytes + 255) & ~(size_t)255;
        return p;
    };
    u16*   xb    = (u16*)alloc((size_t)M * D * 2);
    u16*   wqkvt = (u16*)alloc((size_t)3 * D * D * 2);
    u16*   wot   = (u16*)alloc((size_t)D * D * 2);
    u16*   w1t   = (u16*)alloc((size_t)D * F * 2);
    u16*   w2t   = (u16*)alloc((size_t)D * F * 2);
    u16*   qb    = (u16*)alloc((size_t)M * D * 2);
    u16*   kb    = (u16*)alloc((size_t)M * D * 2);
    u16*   vtg   = (u16*)alloc((size_t)M * D * 2);  // V transposed: [D][M]
    u16*   ctxb  = (u16*)alloc((size_t)M * D * 2);
    float* x1f   = (float*)alloc((size_t)M * D * 4);
    u16*   x1b   = (u16*)alloc((size_t)M * D * 2);
    u16*   ff1b  = (u16*)alloc((size_t)M * F * 2);

    float* p0a = (float*)qb;     // WO partial 0 over qb+kb   (dead after attn)
    float* p1a = (float*)ff1b;   // WO partial 1 over ff1b    (not yet live)
    float* p0b = (float*)qb;     // FF2 partial 0 over qb+kb
    float* p1b = (float*)vtg;    // FF2 partial 1 over vtg+ctxb (dead after WO)

    k_prep<<<6144 + 6912, 256, 0, stream>>>(x, xb, wq, wk, wv, wo, w1, w2,
                                            wqkvt, wot, w1t, w2t);

    k_gemm_qkv<<<dim3(M / 128, 3 * D / 128), 256, 0, stream>>>(
        xb, wqkvt, bq, bk, bv, qb, kb, vtg, M, D, SCALE_Q);

    k_attention<<<dim3(S / 128, B * H), 256, 0, stream>>>(qb, kb, vtg, ctxb, S, D, H, M);

    k_gemm_part<<<dim3(M / 128, D / 128, 2), 256, 0, stream>>>(
        ctxb, wot, p0a, p1a, M, D, D, D / 2);
    k_layernorm2<<<M, 256, 0, stream>>>(p0a, p1a, x, bo, a1, g1, x1f, x1b, D);

    k_gemm<true><<<dim3(M / 128, F / 128), 256, 0, stream>>>(
        x1b, w1t, b1, ff1b, M, F, D);
    k_gemm_part<<<dim3(M / 128, D / 128, 2), 256, 0, stream>>>(
        ff1b, w2t, p0b, p1b, M, D, F, F / 2);
    k_layernorm2<<<M, 256, 0, stream>>>(p0b, p1b, x1f, b2, a2, g2, (float*)d_out, nullptr, D);

    (void)in_sizes; (void)n_in; (void)out_size; (void)ws_size;
}